// Round 1
// baseline (99.702 us; speedup 1.0000x reference)
//
#include <hip/hip_runtime.h>
#include <hip/hip_bf16.h>

// out[b, t] = w[t] * q0[b] + b[t]   (B x T x 1 output, fp32)
// Pure streaming-write kernel: one block per row, float4 vectorized stores.

__global__ __launch_bounds__(256)
void pn_rowkernel(const float* __restrict__ q0,
                  const float4* __restrict__ w4,
                  const float4* __restrict__ b4,
                  float4* __restrict__ out4,
                  int T4) {
    const int row = blockIdx.x;
    const float q = q0[row];
    float4* __restrict__ orow = out4 + (long long)row * T4;
    for (int j = threadIdx.x; j < T4; j += blockDim.x) {
        const float4 wv = w4[j];
        const float4 bv = b4[j];
        float4 o;
        o.x = fmaf(q, wv.x, bv.x);
        o.y = fmaf(q, wv.y, bv.y);
        o.z = fmaf(q, wv.z, bv.z);
        o.w = fmaf(q, wv.w, bv.w);
        orow[j] = o;
    }
}

// Scalar fallback for T not divisible by 4 (not expected here, but safe).
__global__ __launch_bounds__(256)
void pn_rowkernel_scalar(const float* __restrict__ q0,
                         const float* __restrict__ w,
                         const float* __restrict__ b,
                         float* __restrict__ out,
                         int T) {
    const int row = blockIdx.x;
    const float q = q0[row];
    float* __restrict__ orow = out + (long long)row * T;
    for (int j = threadIdx.x; j < T; j += blockDim.x) {
        orow[j] = fmaf(q, w[j], b[j]);
    }
}

extern "C" void kernel_launch(void* const* d_in, const int* in_sizes, int n_in,
                              void* d_out, int out_size, void* d_ws, size_t ws_size,
                              hipStream_t stream) {
    const float* q0 = (const float*)d_in[0];   // [B, 1]
    const float* w  = (const float*)d_in[1];   // [T]
    const float* b  = (const float*)d_in[2];   // [T]
    float* out = (float*)d_out;                // [B, T, 1]

    const int B = in_sizes[0];                 // q0 flat count = B*1
    const int T = in_sizes[1];

    if ((T & 3) == 0) {
        pn_rowkernel<<<B, 256, 0, stream>>>(
            q0,
            reinterpret_cast<const float4*>(w),
            reinterpret_cast<const float4*>(b),
            reinterpret_cast<float4*>(out),
            T >> 2);
    } else {
        pn_rowkernel_scalar<<<B, 256, 0, stream>>>(q0, w, b, out, T);
    }
}

// Round 2
// 97.801 us; speedup vs baseline: 1.0194x; 1.0194x over previous
//
#include <hip/hip_runtime.h>
#include <hip/hip_bf16.h>

// out[b, t] = w[t] * q0[b] + b[t]   (B x T x 1 output, fp32)
// Column-stationary layout: each block owns a 256-float4 chunk of t, keeps
// w/b in registers, loops over rows. Nontemporal float4 stores.

typedef float f32x4 __attribute__((ext_vector_type(4)));

__device__ inline float4 fma4(float q, const float4& w, const float4& b) {
    float4 o;
    o.x = fmaf(q, w.x, b.x);
    o.y = fmaf(q, w.y, b.y);
    o.z = fmaf(q, w.z, b.z);
    o.w = fmaf(q, w.w, b.w);
    return o;
}

__device__ inline void nt_store4(float4 v, float4* p) {
    __builtin_nontemporal_store(*reinterpret_cast<f32x4*>(&v),
                                reinterpret_cast<f32x4*>(p));
}

__global__ __launch_bounds__(256)
void pn_colkernel(const float* __restrict__ q0,
                  const float4* __restrict__ w4,
                  const float4* __restrict__ b4,
                  float4* __restrict__ out4,
                  int T4, int rows_per_blk) {
    const int t4 = blockIdx.y * blockDim.x + threadIdx.x;
    const float4 wv = w4[t4];
    const float4 bv = b4[t4];
    const int r0 = blockIdx.x * rows_per_blk;

    #pragma unroll 1
    for (int r = 0; r < rows_per_blk; r += 4) {
        const float4 qv = *reinterpret_cast<const float4*>(q0 + r0 + r);
        const long long base = (long long)(r0 + r) * T4 + t4;
        nt_store4(fma4(qv.x, wv, bv), out4 + base);
        nt_store4(fma4(qv.y, wv, bv), out4 + base + T4);
        nt_store4(fma4(qv.z, wv, bv), out4 + base + 2LL * T4);
        nt_store4(fma4(qv.w, wv, bv), out4 + base + 3LL * T4);
    }
}

// Fallback: one block per row, float4 stores (previous round's kernel).
__global__ __launch_bounds__(256)
void pn_rowkernel(const float* __restrict__ q0,
                  const float4* __restrict__ w4,
                  const float4* __restrict__ b4,
                  float4* __restrict__ out4,
                  int T4) {
    const int row = blockIdx.x;
    const float q = q0[row];
    float4* __restrict__ orow = out4 + (long long)row * T4;
    for (int j = threadIdx.x; j < T4; j += blockDim.x) {
        orow[j] = fma4(q, w4[j], b4[j]);
    }
}

// Scalar fallback for T not divisible by 4.
__global__ __launch_bounds__(256)
void pn_rowkernel_scalar(const float* __restrict__ q0,
                         const float* __restrict__ w,
                         const float* __restrict__ b,
                         float* __restrict__ out,
                         int T) {
    const int row = blockIdx.x;
    const float q = q0[row];
    float* __restrict__ orow = out + (long long)row * T;
    for (int j = threadIdx.x; j < T; j += blockDim.x) {
        orow[j] = fmaf(q, w[j], b[j]);
    }
}

extern "C" void kernel_launch(void* const* d_in, const int* in_sizes, int n_in,
                              void* d_out, int out_size, void* d_ws, size_t ws_size,
                              hipStream_t stream) {
    const float* q0 = (const float*)d_in[0];   // [B, 1]
    const float* w  = (const float*)d_in[1];   // [T]
    const float* b  = (const float*)d_in[2];   // [T]
    float* out = (float*)d_out;                // [B, T, 1]

    const int B = in_sizes[0];
    const int T = in_sizes[1];

    if ((T & 3) != 0) {
        pn_rowkernel_scalar<<<B, 256, 0, stream>>>(q0, w, b, out, T);
        return;
    }
    const int T4 = T >> 2;

    // Column-stationary path needs T4 % 256 == 0 and B % rows_per_blk == 0.
    const int rows_per_blk = 64;
    if ((T4 % 256) == 0 && (B % rows_per_blk) == 0) {
        dim3 grid(B / rows_per_blk, T4 / 256);
        pn_colkernel<<<grid, 256, 0, stream>>>(
            q0,
            reinterpret_cast<const float4*>(w),
            reinterpret_cast<const float4*>(b),
            reinterpret_cast<float4*>(out),
            T4, rows_per_blk);
    } else {
        pn_rowkernel<<<B, 256, 0, stream>>>(
            q0,
            reinterpret_cast<const float4*>(w),
            reinterpret_cast<const float4*>(b),
            reinterpret_cast<float4*>(out),
            T4);
    }
}